// Round 3
// baseline (863.040 us; speedup 1.0000x reference)
//
#include <hip/hip_runtime.h>
#include <hip/hip_bf16.h>
#include <stdint.h>

#define T_TOK 8192
#define D_DIM 1024
#define H_DIM 2048
#define E_NUM 8
#define KSEL  2
#define NROWS (T_TOK*KSEL)

#define BM 128
#define BN 128
#define BK 64

typedef __bf16 bf16_t;
typedef bf16_t bf16x8 __attribute__((ext_vector_type(8)));
typedef float  f32x4  __attribute__((ext_vector_type(4)));

__device__ __forceinline__ ushort f2bf(float f) {
    uint32_t u = __builtin_bit_cast(uint32_t, f);
    uint32_t r = (u + 0x7FFFu + ((u >> 16) & 1u)) >> 16;   // RNE
    return (ushort)r;
}

// async global->LDS, 16B per lane: wave-uniform LDS base + lane*16 (linear dest),
// per-lane GLOBAL source (gather + swizzle live on the source side).
__device__ __forceinline__ void gload16(const ushort* g, ushort* l) {
    __builtin_amdgcn_global_load_lds(
        (const __attribute__((address_space(1))) void*)g,
        (__attribute__((address_space(3))) void*)l, 16, 0, 0);
}

// ---------------- fp32 -> bf16 bulk convert (weights) ----------------
__global__ __launch_bounds__(256) void convert_kernel(const float* __restrict__ src,
                                                      ushort* __restrict__ dst, int n4) {
    int i = blockIdx.x * 256 + threadIdx.x;
    int stride = gridDim.x * 256;
    for (; i < n4; i += stride) {
        float4 v = *(const float4*)(src + (size_t)i * 4);
        ushort4 o;
        o.x = f2bf(v.x); o.y = f2bf(v.y); o.z = f2bf(v.z); o.w = f2bf(v.w);
        *(ushort4*)(dst + (size_t)i * 4) = o;
    }
}

// ---------------- router: logits, softmax-top2, x->bf16 ----------------
__global__ __launch_bounds__(256) void router_kernel(const float* __restrict__ x,
                                                     const float* __restrict__ rw,
                                                     ushort* __restrict__ x16,
                                                     int* __restrict__ topk_idx,
                                                     float* __restrict__ topk_w,
                                                     int* __restrict__ cnt) {
    const int wid  = threadIdx.x >> 6;
    const int lane = threadIdx.x & 63;
    const int t = blockIdx.x * 4 + wid;
    const float* xr = x + (size_t)t * D_DIM;

    float acc[E_NUM];
#pragma unroll
    for (int e = 0; e < E_NUM; e++) acc[e] = 0.f;

#pragma unroll
    for (int i = 0; i < 4; i++) {
        int d0 = i * 256 + lane * 4;
        float4 xv = *(const float4*)(xr + d0);
        ushort4 o;
        o.x = f2bf(xv.x); o.y = f2bf(xv.y); o.z = f2bf(xv.z); o.w = f2bf(xv.w);
        *(ushort4*)(x16 + (size_t)t * D_DIM + d0) = o;
#pragma unroll
        for (int e = 0; e < E_NUM; e++) {
            float4 wv = *(const float4*)(rw + e * D_DIM + d0);
            acc[e] += xv.x * wv.x + xv.y * wv.y + xv.z * wv.z + xv.w * wv.w;
        }
    }
#pragma unroll
    for (int e = 0; e < E_NUM; e++) {
#pragma unroll
        for (int s = 32; s > 0; s >>= 1) acc[e] += __shfl_xor(acc[e], s);
    }
    int e1 = 0; float m1 = acc[0];
#pragma unroll
    for (int e = 1; e < E_NUM; e++) if (acc[e] > m1) { m1 = acc[e]; e1 = e; }
    int e2 = -1; float m2 = -INFINITY;
#pragma unroll
    for (int e = 0; e < E_NUM; e++) if (e != e1 && acc[e] > m2) { m2 = acc[e]; e2 = e; }
    float w1 = 1.f / (1.f + expf(m2 - m1));
    float w2 = 1.f - w1;
    if (lane == 0) {
        topk_idx[t * 2 + 0] = e1; topk_idx[t * 2 + 1] = e2;
        topk_w  [t * 2 + 0] = w1; topk_w  [t * 2 + 1] = w2;
        atomicAdd(cnt + e1, 1);
        atomicAdd(cnt + e2, 1);
    }
}

// ---------------- tiny prefix sum over 8 experts ----------------
__global__ void prefix_kernel(const int* __restrict__ cnt, int* __restrict__ offs,
                              int* __restrict__ fill) {
    if (threadIdx.x == 0) {
        int s = 0;
        for (int e = 0; e < E_NUM; e++) { offs[e] = s; fill[e] = s; s += cnt[e]; }
        offs[E_NUM] = s;
    }
}

// ---------------- scatter tokens to compacted per-expert rows ----------------
__global__ __launch_bounds__(256) void scatter_kernel(const int* __restrict__ topk_idx,
                                                      int* __restrict__ fill,
                                                      int* __restrict__ row_token,
                                                      int* __restrict__ rowmap) {
    int t = blockIdx.x * 256 + threadIdx.x;
#pragma unroll
    for (int k = 0; k < KSEL; k++) {
        int e = topk_idx[t * 2 + k];
        int pos = atomicAdd(fill + e, 1);
        row_token[pos] = t;
        rowmap[t * 2 + k] = pos;       // inverse map for combine
    }
}

// ---------------- grouped GEMM: gate+up fused, SiLU epilogue ----------------
__global__ __launch_bounds__(512) void gateup_kernel(const ushort* __restrict__ x16,
                                                     const ushort* __restrict__ wg16,
                                                     const ushort* __restrict__ wu16,
                                                     const int* __restrict__ offs,
                                                     const int* __restrict__ row_token,
                                                     ushort* __restrict__ h16) {
    const int e = blockIdx.z;
    const int off_e = offs[e];
    const int n_e = offs[e + 1] - off_e;
    const int m0 = blockIdx.y * BM;
    if (m0 >= n_e) return;            // uniform across block: safe
    const int n0 = blockIdx.x * BN;

    __shared__ __align__(16) ushort sA[BM * BK];
    __shared__ __align__(16) ushort sBg[BN * BK];
    __shared__ __align__(16) ushort sBu[BN * BK];
    __shared__ int sTok[BM];

    const int tid = threadIdx.x;
    if (tid < BM) {
        int r = m0 + tid;
        sTok[tid] = row_token[off_e + (r < n_e ? r : n_e - 1)];
    }
    __syncthreads();

    const int wid = tid >> 6, lane = tid & 63;
    // staging geometry: wave stages segments s0,s1 (8 rows x 64 cols each, 1KB)
    const int s0 = wid * 2, s1 = s0 + 1;
    const int lrow = lane >> 3;              // 0..7 row within segment
    const int lcol = lane & 7;               // 0..7 16B-chunk within row
    const int xc = ((lcol ^ lrow) * 8);      // pre-swizzled source chunk (ushorts)
    const int rA0 = s0 * 8 + lrow, rA1 = s1 * 8 + lrow;   // row&7 == lrow

    const ushort* gA0 = x16 + (size_t)sTok[rA0] * D_DIM + xc;
    const ushort* gA1 = x16 + (size_t)sTok[rA1] * D_DIM + xc;
    const ushort* gG0 = wg16 + ((size_t)e * H_DIM + n0 + rA0) * D_DIM + xc;
    const ushort* gG1 = wg16 + ((size_t)e * H_DIM + n0 + rA1) * D_DIM + xc;
    const ushort* gU0 = wu16 + ((size_t)e * H_DIM + n0 + rA0) * D_DIM + xc;
    const ushort* gU1 = wu16 + ((size_t)e * H_DIM + n0 + rA1) * D_DIM + xc;
    ushort* lA0 = sA  + s0 * 512; ushort* lA1 = sA  + s1 * 512;
    ushort* lG0 = sBg + s0 * 512; ushort* lG1 = sBg + s1 * 512;
    ushort* lU0 = sBu + s0 * 512; ushort* lU1 = sBu + s1 * 512;

    const int wr = wid >> 2, wc = wid & 3;   // 2x4 wave grid, 64x32 per wave
    const int fr = lane & 15, fq = lane >> 4;

    f32x4 accg[4][2], accu[4][2];
    f32x4 z4 = {0.f, 0.f, 0.f, 0.f};
#pragma unroll
    for (int m = 0; m < 4; m++)
#pragma unroll
        for (int n = 0; n < 2; n++) { accg[m][n] = z4; accu[m][n] = z4; }

    const int NKT = D_DIM / BK;   // 16
    for (int kt = 0; kt < NKT; ++kt) {
        gload16(gA0, lA0); gload16(gA1, lA1);
        gload16(gG0, lG0); gload16(gG1, lG1);
        gload16(gU0, lU0); gload16(gU1, lU1);
        gA0 += BK; gA1 += BK; gG0 += BK; gG1 += BK; gU0 += BK; gU1 += BK;
        __syncthreads();   // compiler drains vmcnt before barrier (m97 structure)
#pragma unroll
        for (int ks = 0; ks < 2; ++ks) {
            bf16x8 af[4], bg[2], bu[2];
#pragma unroll
            for (int m = 0; m < 4; m++) {
                int r = wr * 64 + m * 16 + fr;
                af[m] = *(const bf16x8*)&sA[r * BK + (((ks * 4 + fq) ^ (r & 7)) * 8)];
            }
#pragma unroll
            for (int n = 0; n < 2; n++) {
                int c = wc * 32 + n * 16 + fr;
                int sl = ((ks * 4 + fq) ^ (c & 7)) * 8;
                bg[n] = *(const bf16x8*)&sBg[c * BK + sl];
                bu[n] = *(const bf16x8*)&sBu[c * BK + sl];
            }
#pragma unroll
            for (int m = 0; m < 4; m++)
#pragma unroll
                for (int n = 0; n < 2; n++) {
                    accg[m][n] = __builtin_amdgcn_mfma_f32_16x16x32_bf16(af[m], bg[n], accg[m][n], 0, 0, 0);
                    accu[m][n] = __builtin_amdgcn_mfma_f32_16x16x32_bf16(af[m], bu[n], accu[m][n], 0, 0, 0);
                }
        }
        __syncthreads();
    }

#pragma unroll
    for (int m = 0; m < 4; m++)
#pragma unroll
        for (int n = 0; n < 2; n++) {
            int col = n0 + wc * 32 + n * 16 + fr;
#pragma unroll
            for (int v = 0; v < 4; v++) {
                int grow = m0 + wr * 64 + m * 16 + fq * 4 + v;
                if (grow < n_e) {
                    float g = accg[m][n][v], u = accu[m][n][v];
                    float h = g / (1.f + expf(-g)) * u;
                    h16[(size_t)(off_e + grow) * H_DIM + col] = f2bf(h);
                }
            }
        }
}

// ---------------- grouped GEMM: down proj -> per-row y (no atomics) ----------------
__global__ __launch_bounds__(512) void down_kernel(const ushort* __restrict__ h16,
                                                   const ushort* __restrict__ wd16,
                                                   const int* __restrict__ offs,
                                                   float* __restrict__ y) {
    const int e = blockIdx.z;
    const int off_e = offs[e];
    const int n_e = offs[e + 1] - off_e;
    const int m0 = blockIdx.y * BM;
    if (m0 >= n_e) return;
    const int n0 = blockIdx.x * BN;

    __shared__ __align__(16) ushort sA[BM * BK];
    __shared__ __align__(16) ushort sB[BN * BK];

    const int tid = threadIdx.x;
    const int wid = tid >> 6, lane = tid & 63;
    const int s0 = wid * 2, s1 = s0 + 1;
    const int lrow = lane >> 3;
    const int lcol = lane & 7;
    const int xc = ((lcol ^ lrow) * 8);
    int ar0 = m0 + s0 * 8 + lrow; if (ar0 >= n_e) ar0 = n_e - 1;
    int ar1 = m0 + s1 * 8 + lrow; if (ar1 >= n_e) ar1 = n_e - 1;

    const ushort* gA0 = h16 + (size_t)(off_e + ar0) * H_DIM + xc;
    const ushort* gA1 = h16 + (size_t)(off_e + ar1) * H_DIM + xc;
    const ushort* gB0 = wd16 + ((size_t)e * D_DIM + n0 + s0 * 8 + lrow) * H_DIM + xc;
    const ushort* gB1 = wd16 + ((size_t)e * D_DIM + n0 + s1 * 8 + lrow) * H_DIM + xc;
    ushort* lA0 = sA + s0 * 512; ushort* lA1 = sA + s1 * 512;
    ushort* lB0 = sB + s0 * 512; ushort* lB1 = sB + s1 * 512;

    const int wr = wid >> 2, wc = wid & 3;
    const int fr = lane & 15, fq = lane >> 4;

    f32x4 acc[4][2];
    f32x4 z4 = {0.f, 0.f, 0.f, 0.f};
#pragma unroll
    for (int m = 0; m < 4; m++)
#pragma unroll
        for (int n = 0; n < 2; n++) acc[m][n] = z4;

    const int NKT = H_DIM / BK;   // 32
    for (int kt = 0; kt < NKT; ++kt) {
        gload16(gA0, lA0); gload16(gA1, lA1);
        gload16(gB0, lB0); gload16(gB1, lB1);
        gA0 += BK; gA1 += BK; gB0 += BK; gB1 += BK;
        __syncthreads();
#pragma unroll
        for (int ks = 0; ks < 2; ++ks) {
            bf16x8 af[4], bf[2];
#pragma unroll
            for (int m = 0; m < 4; m++) {
                int r = wr * 64 + m * 16 + fr;
                af[m] = *(const bf16x8*)&sA[r * BK + (((ks * 4 + fq) ^ (r & 7)) * 8)];
            }
#pragma unroll
            for (int n = 0; n < 2; n++) {
                int c = wc * 32 + n * 16 + fr;
                bf[n] = *(const bf16x8*)&sB[c * BK + (((ks * 4 + fq) ^ (c & 7)) * 8)];
            }
#pragma unroll
            for (int m = 0; m < 4; m++)
#pragma unroll
                for (int n = 0; n < 2; n++)
                    acc[m][n] = __builtin_amdgcn_mfma_f32_16x16x32_bf16(af[m], bf[n], acc[m][n], 0, 0, 0);
        }
        __syncthreads();
    }

#pragma unroll
    for (int m = 0; m < 4; m++)
#pragma unroll
        for (int n = 0; n < 2; n++) {
            int col = n0 + wc * 32 + n * 16 + fr;
#pragma unroll
            for (int v = 0; v < 4; v++) {
                int grow = m0 + wr * 64 + m * 16 + fq * 4 + v;
                if (grow < n_e)
                    y[(size_t)(off_e + grow) * D_DIM + col] = acc[m][n][v];
            }
        }
}

// ---------------- combine: out[t] = w0*y[r0] + w1*y[r1] ----------------
__global__ __launch_bounds__(256) void combine_kernel(const float* __restrict__ y,
                                                      const int* __restrict__ rowmap,
                                                      const float* __restrict__ topk_w,
                                                      float* __restrict__ out) {
    const int t = blockIdx.x;
    const int d = threadIdx.x * 4;
    const int r0 = rowmap[t * 2], r1 = rowmap[t * 2 + 1];
    const float w0 = topk_w[t * 2], w1 = topk_w[t * 2 + 1];
    float4 a = *(const float4*)(y + (size_t)r0 * D_DIM + d);
    float4 b = *(const float4*)(y + (size_t)r1 * D_DIM + d);
    float4 o;
    o.x = w0 * a.x + w1 * b.x;
    o.y = w0 * a.y + w1 * b.y;
    o.z = w0 * a.z + w1 * b.z;
    o.w = w0 * a.w + w1 * b.w;
    *(float4*)(out + (size_t)t * D_DIM + d) = o;
}

extern "C" void kernel_launch(void* const* d_in, const int* in_sizes, int n_in,
                              void* d_out, int out_size, void* d_ws, size_t ws_size,
                              hipStream_t stream) {
    const float* x  = (const float*)d_in[0];
    const float* rw = (const float*)d_in[1];
    const float* wg = (const float*)d_in[2];
    const float* wu = (const float*)d_in[3];
    const float* wd = (const float*)d_in[4];
    float* out = (float*)d_out;

    char* p = (char*)d_ws;
    size_t off = 0;
    auto alloc = [&](size_t b) { size_t c = off; off = (off + b + 255) & ~(size_t)255; return c; };
    size_t ctrl_o = alloc(256);
    size_t tki_o  = alloc((size_t)T_TOK * KSEL * 4);
    size_t tkw_o  = alloc((size_t)T_TOK * KSEL * 4);
    size_t rtok_o = alloc((size_t)NROWS * 4);
    size_t rmap_o = alloc((size_t)NROWS * 4);
    size_t x16_o  = alloc((size_t)T_TOK * D_DIM * 2);
    size_t wg16_o = alloc((size_t)E_NUM * H_DIM * D_DIM * 2);
    size_t wu16_o = alloc((size_t)E_NUM * H_DIM * D_DIM * 2);
    size_t wd16_o = alloc((size_t)E_NUM * D_DIM * H_DIM * 2);
    size_t h16_o  = alloc((size_t)NROWS * H_DIM * 2);
    if (off > ws_size) return;   // insufficient workspace -> visible failure

    int*    cnt       = (int*)(p + ctrl_o);           // 8 ints
    int*    offs      = (int*)(p + ctrl_o + 64);      // 9 ints
    int*    fill      = (int*)(p + ctrl_o + 128);     // 8 ints
    int*    topk_idx  = (int*)(p + tki_o);
    float*  topk_w    = (float*)(p + tkw_o);
    int*    row_token = (int*)(p + rtok_o);
    int*    rowmap    = (int*)(p + rmap_o);
    ushort* x16  = (ushort*)(p + x16_o);
    ushort* wg16 = (ushort*)(p + wg16_o);
    ushort* wu16 = (ushort*)(p + wu16_o);
    ushort* wd16 = (ushort*)(p + wd16_o);
    ushort* h16  = (ushort*)(p + h16_o);
    // y (NROWS*D*4 = 64 MiB) aliases wg16+wu16 (2*32 MiB) — both dead after gateup
    float*  y    = (float*)(p + wg16_o);

    hipMemsetAsync(p + ctrl_o, 0, 256, stream);

    const int n4w = (E_NUM * H_DIM * D_DIM) / 4;
    convert_kernel<<<1024, 256, 0, stream>>>(wg, wg16, n4w);
    convert_kernel<<<1024, 256, 0, stream>>>(wu, wu16, n4w);
    convert_kernel<<<1024, 256, 0, stream>>>(wd, wd16, n4w);

    router_kernel<<<T_TOK / 4, 256, 0, stream>>>(x, rw, x16, topk_idx, topk_w, cnt);
    prefix_kernel<<<1, 64, 0, stream>>>(cnt, offs, fill);
    scatter_kernel<<<T_TOK / 256, 256, 0, stream>>>(topk_idx, fill, row_token, rowmap);

    gateup_kernel<<<dim3(H_DIM / BN, T_TOK / BM, E_NUM), 512, 0, stream>>>(
        x16, wg16, wu16, offs, row_token, h16);
    down_kernel<<<dim3(D_DIM / BN, T_TOK / BM, E_NUM), 512, 0, stream>>>(
        h16, wd16, offs, y);
    combine_kernel<<<T_TOK, 256, 0, stream>>>(y, rowmap, topk_w, out);
}